// Round 2
// baseline (432.637 us; speedup 1.0000x reference)
//
#include <hip/hip_runtime.h>
#include <hip/hip_bf16.h>
#include <cstdint>

typedef __bf16 bf16_t;
typedef __attribute__((ext_vector_type(8))) __bf16 bf16x8;
typedef __attribute__((ext_vector_type(4))) __bf16 bf16x4;
typedef __attribute__((ext_vector_type(4))) float f32x4;

#define S_LEN 2048
#define D_MODEL 2048
#define NH 16
#define NKV 4
#define HD_ 128

#define MFMA16(a, b, c) __builtin_amdgcn_mfma_f32_16x16x32_bf16((a), (b), (c), 0, 0, 0)

// Async global->LDS, 16B per lane. LDS dest must be WAVE-UNIFORM base; HW adds lane*16.
__device__ __forceinline__ void gload_lds16(const void* g, void* l) {
  __builtin_amdgcn_global_load_lds((__attribute__((address_space(1))) void*)((void*)g),
                                   (__attribute__((address_space(3))) void*)(l), 16, 0, 0);
}

// ---------------------------------------------------------------- prep kernels
__global__ __launch_bounds__(256) void cast_x_kernel(const float* __restrict__ in,
                                                     bf16_t* __restrict__ out, int n4) {
  int i = blockIdx.x * 256 + threadIdx.x;
  if (i >= n4) return;
  float4 v = reinterpret_cast<const float4*>(in)[i];
  bf16x4 o = {(__bf16)v.x, (__bf16)v.y, (__bf16)v.z, (__bf16)v.w};
  *reinterpret_cast<bf16x4*>(out + (size_t)i * 4) = o;
}

// in: R x Cc fp32 (ld=ldin, grid = (Cc/32, R/32)); out: Cc x R bf16 (ld=ldout)
__global__ void transpose_cast_kernel(const float* __restrict__ in, bf16_t* __restrict__ out,
                                      int ldin, int ldout) {
  __shared__ float t[32][33];
  int c0 = blockIdx.x * 32, r0 = blockIdx.y * 32;
  int x = threadIdx.x, y = threadIdx.y;
  t[y][x] = in[(size_t)(r0 + y) * ldin + (c0 + x)];
  __syncthreads();
  out[(size_t)(c0 + y) * ldout + (r0 + x)] = (__bf16)t[x][y];
}

__global__ __launch_bounds__(256) void rope_q_kernel(const float* __restrict__ qkv,
    const float* __restrict__ cosT, const float* __restrict__ sinT, bf16_t* __restrict__ Qb) {
  int s = blockIdx.x;
#pragma unroll
  for (int i = 0; i < 4; ++i) {
    int p = i * 256 + threadIdx.x;  // 0..1023 = 16 heads x 64 pairs
    int h = p >> 6, j = p & 63;
    float c = cosT[s * 64 + j], sn = sinT[s * 64 + j];
    const float* src = qkv + (size_t)s * 3072 + h * 128 + 2 * j;
    float x0 = src[0], x1 = src[1];
    bf16_t* dst = Qb + ((size_t)h * S_LEN + s) * HD_ + 2 * j;
    dst[0] = (__bf16)(x0 * c - x1 * sn);
    dst[1] = (__bf16)(x0 * sn + x1 * c);
  }
}

__global__ __launch_bounds__(256) void rope_k_kernel(const float* __restrict__ qkv,
    const float* __restrict__ cosT, const float* __restrict__ sinT, bf16_t* __restrict__ Kb) {
  int s = blockIdx.x;
  int p = threadIdx.x;  // 0..255 = 4 kv heads x 64 pairs
  int kv = p >> 6, j = p & 63;
  float c = cosT[s * 64 + j], sn = sinT[s * 64 + j];
  const float* src = qkv + (size_t)s * 3072 + 2048 + kv * 128 + 2 * j;
  float x0 = src[0], x1 = src[1];
  bf16_t* dst = Kb + ((size_t)kv * S_LEN + s) * HD_ + 2 * j;
  dst[0] = (__bf16)(x0 * c - x1 * sn);
  dst[1] = (__bf16)(x0 * sn + x1 * c);
}

// ---------------------------------------------------------------- GEMM (m97 structure)
// A: MxK bf16 row-major.  B: NxK bf16 (i.e. W^T).  C: MxN fp32.
// 128x128 tile, BK=64, 256 threads (2x2 waves), global_load_lds w/ T2 XOR swizzle.
#define BM 128
#define BN 128
#define BK 64

__global__ __launch_bounds__(256) void gemm_bf16_kernel(const bf16_t* __restrict__ A,
    const bf16_t* __restrict__ B, float* __restrict__ C, int M, int N, int K) {
  __shared__ __attribute__((aligned(16))) bf16_t aL[BM * BK];
  __shared__ __attribute__((aligned(16))) bf16_t bL[BN * BK];
  const int tid = threadIdx.x;
  const int wave = tid >> 6, lane = tid & 63;
  const int wr = wave >> 1, wc = wave & 1;
  const int l15 = lane & 15, l4 = lane >> 4;
  const int bm = blockIdx.y * BM, bn = blockIdx.x * BN;

  f32x4 zero = {0.f, 0.f, 0.f, 0.f};
  f32x4 acc[4][4];
#pragma unroll
  for (int m = 0; m < 4; ++m)
#pragma unroll
    for (int n = 0; n < 4; ++n) acc[m][n] = zero;

  // Staging: 1024 16B-chunks per operand tile; chunk ci: LDS row r=ci>>3, stored chunk cs=ci&7
  // holds logical k-chunk cl = cs ^ (r&7)  (pre-swizzled global source, linear LDS dest).
  const bf16_t* aSrc[4];
  const bf16_t* bSrc[4];
  bf16_t* aDst[4];
  bf16_t* bDst[4];
#pragma unroll
  for (int i = 0; i < 4; ++i) {
    int ci = i * 256 + tid;
    int r = ci >> 3;
    int cl = (ci & 7) ^ (r & 7);
    aSrc[i] = A + (size_t)(bm + r) * K + cl * 8;
    bSrc[i] = B + (size_t)(bn + r) * K + cl * 8;
    aDst[i] = aL + (i * 256 + wave * 64) * 8;  // wave-uniform base
    bDst[i] = bL + (i * 256 + wave * 64) * 8;
  }

  for (int kt = 0; kt < K; kt += BK) {
#pragma unroll
    for (int i = 0; i < 4; ++i) gload_lds16(aSrc[i] + kt, aDst[i]);
#pragma unroll
    for (int i = 0; i < 4; ++i) gload_lds16(bSrc[i] + kt, bDst[i]);
    __syncthreads();
#pragma unroll
    for (int t = 0; t < 2; ++t) {
      bf16x8 af[4], bfr[4];
#pragma unroll
      for (int f = 0; f < 4; ++f) {
        int Ra = wr * 64 + f * 16 + l15;
        int ca = (t * 4 + l4) ^ (Ra & 7);
        af[f] = *reinterpret_cast<const bf16x8*>(aL + Ra * 64 + ca * 8);
        int Rb = wc * 64 + f * 16 + l15;
        int cb = (t * 4 + l4) ^ (Rb & 7);
        bfr[f] = *reinterpret_cast<const bf16x8*>(bL + Rb * 64 + cb * 8);
      }
#pragma unroll
      for (int m = 0; m < 4; ++m)
#pragma unroll
        for (int n = 0; n < 4; ++n) acc[m][n] = MFMA16(af[m], bfr[n], acc[m][n]);
    }
    __syncthreads();
  }

#pragma unroll
  for (int m = 0; m < 4; ++m) {
    int row0 = bm + wr * 64 + m * 16 + l4 * 4;
#pragma unroll
    for (int n = 0; n < 4; ++n) {
      int col = bn + wc * 64 + n * 16 + l15;
#pragma unroll
      for (int r = 0; r < 4; ++r) C[(size_t)(row0 + r) * N + col] = acc[m][n][r];
    }
  }
}

// ---------------------------------------------------------------- differential flash attention
// Qb: [H][S][HD] bf16 (rope'd).  Kb: [KV][S][HD] bf16 (rope'd).  VTb: [KV][HD][S] bf16.
// Block = (q-tile of 64 rows) x head. 4 waves x 16 q-rows. KV tiles of 64.
__global__ __launch_bounds__(256) void diff_attn_kernel(const bf16_t* __restrict__ Qb,
    const bf16_t* __restrict__ Kb, const bf16_t* __restrict__ VTb,
    const float* __restrict__ lambda_param, bf16_t* __restrict__ attn) {
  const int h = blockIdx.y;
  const int kvh = h >> 2;  // REP = 4
  const int q0 = blockIdx.x * 64;
  const int tid = threadIdx.x, wave = tid >> 6, lane = tid & 63;
  const int l15 = lane & 15, l4 = lane >> 4;

  __shared__ __attribute__((aligned(16))) bf16_t kL[64 * 128];   // [kv][hd], 16 chunks/row, swz
  __shared__ __attribute__((aligned(16))) bf16_t vL[128 * 64];   // [d][kv],  8 chunks/row, swz
  __shared__ __attribute__((aligned(16))) bf16_t pL[4][2][16 * 64];  // per-wave P1/P2, swz

  // Q fragments: A-operand rows = lane&15; f=0,1 -> hd 0..63 (half1), f=2,3 -> hd 64..127
  const bf16_t* qp = Qb + ((size_t)h * S_LEN + q0 + wave * 16 + l15) * HD_;
  bf16x8 qf[4];
#pragma unroll
  for (int f = 0; f < 4; ++f) qf[f] = *reinterpret_cast<const bf16x8*>(qp + f * 32 + l4 * 8);

  f32x4 zero = {0.f, 0.f, 0.f, 0.f};
  f32x4 o1[8], o2[8];
#pragma unroll
  for (int n = 0; n < 8; ++n) { o1[n] = zero; o2[n] = zero; }
  float m1[4], l1[4], m2[4], l2[4];
#pragma unroll
  for (int r = 0; r < 4; ++r) { m1[r] = -INFINITY; m2[r] = -INFINITY; l1[r] = 0.f; l2[r] = 0.f; }

  const bf16_t* kSrc[4]; bf16_t* kDst[4];
  const bf16_t* vSrc[4]; bf16_t* vDst[4];
#pragma unroll
  for (int i = 0; i < 4; ++i) {
    int ci = i * 256 + tid;
    {
      int r = ci >> 4, cs = ci & 15;
      int cl = cs ^ (r & 7);
      kSrc[i] = Kb + ((size_t)kvh * S_LEN + r) * HD_ + cl * 8;
      kDst[i] = kL + (i * 256 + wave * 64) * 8;
    }
    {
      int r = ci >> 3, cs = ci & 7;
      int cl = cs ^ (r & 7);
      vSrc[i] = VTb + ((size_t)kvh * HD_ + r) * S_LEN + cl * 8;
      vDst[i] = vL + (i * 256 + wave * 64) * 8;
    }
  }

  const int rowg0 = q0 + wave * 16 + l4 * 4;  // + r = global q row

  for (int kv0 = 0; kv0 <= q0; kv0 += 64) {
#pragma unroll
    for (int i = 0; i < 4; ++i) gload_lds16(kSrc[i] + (size_t)kv0 * HD_, kDst[i]);
#pragma unroll
    for (int i = 0; i < 4; ++i) gload_lds16(vSrc[i] + kv0, vDst[i]);
    __syncthreads();

    // scores: S1 (hd 0..63) and S2 (hd 64..127), 16q x 64kv per wave
    f32x4 s1[4], s2[4];
#pragma unroll
    for (int n = 0; n < 4; ++n) { s1[n] = zero; s2[n] = zero; }
#pragma unroll
    for (int t = 0; t < 2; ++t) {
#pragma unroll
      for (int n = 0; n < 4; ++n) {
        int Rk = n * 16 + l15;
        int c1 = (t * 4 + l4) ^ (Rk & 7);
        int c2 = (8 + t * 4 + l4) ^ (Rk & 7);
        bf16x8 kf1 = *reinterpret_cast<const bf16x8*>(kL + Rk * 128 + c1 * 8);
        bf16x8 kf2 = *reinterpret_cast<const bf16x8*>(kL + Rk * 128 + c2 * 8);
        s1[n] = MFMA16(qf[t], kf1, s1[n]);
        s2[n] = MFMA16(qf[2 + t], kf2, s2[n]);
      }
    }

    const bool diag = (kv0 == q0);
    float scl1[4], scl2[4];
#pragma unroll
    for (int r = 0; r < 4; ++r) {
      float pm1 = -INFINITY, pm2 = -INFINITY;
#pragma unroll
      for (int n = 0; n < 4; ++n) {
        float v1 = s1[n][r] * 0.125f, v2 = s2[n][r] * 0.125f;
        if (diag && (kv0 + n * 16 + l15 > rowg0 + r)) { v1 = -1e30f; v2 = -1e30f; }
        s1[n][r] = v1; s2[n][r] = v2;
        pm1 = fmaxf(pm1, v1); pm2 = fmaxf(pm2, v2);
      }
#pragma unroll
      for (int off = 1; off < 16; off <<= 1) {
        pm1 = fmaxf(pm1, __shfl_xor(pm1, off, 64));
        pm2 = fmaxf(pm2, __shfl_xor(pm2, off, 64));
      }
      float mn1 = fmaxf(m1[r], pm1), mn2 = fmaxf(m2[r], pm2);
      float sc1 = __expf(m1[r] - mn1), sc2 = __expf(m2[r] - mn2);
      m1[r] = mn1; m2[r] = mn2;
      float rs1 = 0.f, rs2 = 0.f;
#pragma unroll
      for (int n = 0; n < 4; ++n) {
        int kvloc = n * 16 + l15;
        int q = l4 * 4 + r;
        int cs = (kvloc >> 3) ^ (q & 7);
        float p1 = __expf(s1[n][r] - mn1);
        float p2 = __expf(s2[n][r] - mn2);
        rs1 += p1; rs2 += p2;
        pL[wave][0][q * 64 + cs * 8 + (kvloc & 7)] = (__bf16)p1;
        pL[wave][1][q * 64 + cs * 8 + (kvloc & 7)] = (__bf16)p2;
      }
#pragma unroll
      for (int off = 1; off < 16; off <<= 1) {
        rs1 += __shfl_xor(rs1, off, 64);
        rs2 += __shfl_xor(rs2, off, 64);
      }
      l1[r] = l1[r] * sc1 + rs1;
      l2[r] = l2[r] * sc2 + rs2;
      scl1[r] = sc1; scl2[r] = sc2;
    }
#pragma unroll
    for (int n = 0; n < 8; ++n)
#pragma unroll
      for (int r = 0; r < 4; ++r) { o1[n][r] *= scl1[r]; o2[n][r] *= scl2[r]; }

    // PV: O += P(16x64) * V(64x128); A-operand P from per-wave LDS, B-operand from vL (V^T tile)
#pragma unroll
    for (int t = 0; t < 2; ++t) {
      int cp = (t * 4 + l4) ^ (l15 & 7);
      bf16x8 pf1 = *reinterpret_cast<const bf16x8*>(&pL[wave][0][l15 * 64 + cp * 8]);
      bf16x8 pf2 = *reinterpret_cast<const bf16x8*>(&pL[wave][1][l15 * 64 + cp * 8]);
#pragma unroll
      for (int n = 0; n < 8; ++n) {
        int Rv = n * 16 + l15;
        int cv = (t * 4 + l4) ^ (Rv & 7);
        bf16x8 vf = *reinterpret_cast<const bf16x8*>(vL + Rv * 64 + cv * 8);
        o1[n] = MFMA16(pf1, vf, o1[n]);
        o2[n] = MFMA16(pf2, vf, o2[n]);
      }
    }
    __syncthreads();
  }

  float lam = 1.f / (1.f + __expf(-lambda_param[h]));
  float i1[4], i2[4];
#pragma unroll
  for (int r = 0; r < 4; ++r) { i1[r] = 1.f / l1[r]; i2[r] = lam / l2[r]; }
#pragma unroll
  for (int n = 0; n < 8; ++n) {
    int col = h * HD_ + n * 16 + l15;
#pragma unroll
    for (int r = 0; r < 4; ++r) {
      float v = (o1[n][r] * i1[r] - o2[n][r] * i2[r]) * 0.5f;  // OUT_SCALE = 0.5
      attn[(size_t)(rowg0 + r) * D_MODEL + col] = (__bf16)v;
    }
  }
}

// ---------------------------------------------------------------- launch
extern "C" void kernel_launch(void* const* d_in, const int* in_sizes, int n_in,
                              void* d_out, int out_size, void* d_ws, size_t ws_size,
                              hipStream_t stream) {
  const float* x    = (const float*)d_in[0];
  const float* fcos = (const float*)d_in[1];
  const float* fsin = (const float*)d_in[2];
  const float* Wq   = (const float*)d_in[3];
  const float* Wk   = (const float*)d_in[4];
  const float* Wv   = (const float*)d_in[5];
  const float* Wo   = (const float*)d_in[6];
  const float* lam  = (const float*)d_in[7];
  float* out = (float*)d_out;

  // workspace layout (52 MB total, phases overlap dead regions):
  //  [0,8)   xb      (phase1: qkv gemm input)   -> attnb (phase3)
  //  [8,20)  WqkvT   (phase1)                   -> Qb [8,16) + Kb [16,18) + VT [18,20)
  //  [20,28) WoT     (live until final gemm)
  //  [28,52) QKV fp32
  char* w = (char*)d_ws;
  bf16_t* xb    = (bf16_t*)(w);
  bf16_t* attnb = (bf16_t*)(w);
  bf16_t* WqkvT = (bf16_t*)(w + (8ull << 20));
  bf16_t* Qb    = (bf16_t*)(w + (8ull << 20));
  bf16_t* Kb    = (bf16_t*)(w + (16ull << 20));
  bf16_t* VT    = (bf16_t*)(w + (18ull << 20));
  bf16_t* WoT   = (bf16_t*)(w + (20ull << 20));
  float*  QKV   = (float*) (w + (28ull << 20));

  dim3 tb(32, 32);
  cast_x_kernel<<<4096, 256, 0, stream>>>(x, xb, 1048576);
  transpose_cast_kernel<<<dim3(64, 64), tb, 0, stream>>>(Wq, WqkvT, 2048, 2048);
  transpose_cast_kernel<<<dim3(16, 64), tb, 0, stream>>>(Wk, WqkvT + 2048 * 2048, 512, 2048);
  transpose_cast_kernel<<<dim3(16, 64), tb, 0, stream>>>(Wv, WqkvT + 2560 * 2048, 512, 2048);
  transpose_cast_kernel<<<dim3(64, 64), tb, 0, stream>>>(Wo, WoT, 2048, 2048);

  gemm_bf16_kernel<<<dim3(24, 16), 256, 0, stream>>>(xb, WqkvT, QKV, 2048, 3072, 2048);

  // WqkvT dead from here; Qb/Kb/VT alias its storage.
  rope_q_kernel<<<2048, 256, 0, stream>>>(QKV, fcos, fsin, Qb);
  rope_k_kernel<<<2048, 256, 0, stream>>>(QKV, fcos, fsin, Kb);
  transpose_cast_kernel<<<dim3(16, 64), tb, 0, stream>>>(QKV + 2560, VT, 3072, 2048);

  // xb dead from here; attnb aliases its storage.
  diff_attn_kernel<<<dim3(32, 16), 256, 0, stream>>>(Qb, Kb, VT, lam, attnb);

  gemm_bf16_kernel<<<dim3(16, 16), 256, 0, stream>>>(attnb, WoT, out, 2048, 2048, 2048);
}

// Round 3
// 299.543 us; speedup vs baseline: 1.4443x; 1.4443x over previous
//
#include <hip/hip_runtime.h>
#include <hip/hip_bf16.h>
#include <cstdint>

typedef __bf16 bf16_t;
typedef __attribute__((ext_vector_type(8))) __bf16 bf16x8;
typedef __attribute__((ext_vector_type(4))) __bf16 bf16x4;
typedef __attribute__((ext_vector_type(4))) float f32x4;

#define S_LEN 2048
#define D_MODEL 2048
#define NH 16
#define NKV 4
#define HD_ 128

#define MFMA16(a, b, c) __builtin_amdgcn_mfma_f32_16x16x32_bf16((a), (b), (c), 0, 0, 0)

// Async global->LDS, 16B per lane. LDS dest must be WAVE-UNIFORM base; HW adds lane*16.
__device__ __forceinline__ void gload_lds16(const void* g, void* l) {
  __builtin_amdgcn_global_load_lds((__attribute__((address_space(1))) void*)((void*)g),
                                   (__attribute__((address_space(3))) void*)(l), 16, 0, 0);
}

// ---------------------------------------------------------------- prep kernels
__global__ __launch_bounds__(256) void cast_x_kernel(const float* __restrict__ in,
                                                     bf16_t* __restrict__ out, int n4) {
  int i = blockIdx.x * 256 + threadIdx.x;
  if (i >= n4) return;
  float4 v = reinterpret_cast<const float4*>(in)[i];
  bf16x4 o = {(__bf16)v.x, (__bf16)v.y, (__bf16)v.z, (__bf16)v.w};
  *reinterpret_cast<bf16x4*>(out + (size_t)i * 4) = o;
}

// in: R x Cc fp32 (ld=ldin, grid = (Cc/32, R/32)); out: Cc x R bf16 (ld=ldout)
__global__ void transpose_cast_kernel(const float* __restrict__ in, bf16_t* __restrict__ out,
                                      int ldin, int ldout) {
  __shared__ float t[32][33];
  int c0 = blockIdx.x * 32, r0 = blockIdx.y * 32;
  int x = threadIdx.x, y = threadIdx.y;
  t[y][x] = in[(size_t)(r0 + y) * ldin + (c0 + x)];
  __syncthreads();
  out[(size_t)(c0 + y) * ldout + (r0 + x)] = (__bf16)t[x][y];
}

__global__ __launch_bounds__(256) void rope_q_kernel(const float* __restrict__ qkv,
    const float* __restrict__ cosT, const float* __restrict__ sinT, bf16_t* __restrict__ Qb) {
  int s = blockIdx.x;
#pragma unroll
  for (int i = 0; i < 4; ++i) {
    int p = i * 256 + threadIdx.x;  // 0..1023 = 16 heads x 64 pairs
    int h = p >> 6, j = p & 63;
    float c = cosT[s * 64 + j], sn = sinT[s * 64 + j];
    const float* src = qkv + (size_t)s * 3072 + h * 128 + 2 * j;
    float x0 = src[0], x1 = src[1];
    bf16_t* dst = Qb + ((size_t)h * S_LEN + s) * HD_ + 2 * j;
    dst[0] = (__bf16)(x0 * c - x1 * sn);
    dst[1] = (__bf16)(x0 * sn + x1 * c);
  }
}

__global__ __launch_bounds__(256) void rope_k_kernel(const float* __restrict__ qkv,
    const float* __restrict__ cosT, const float* __restrict__ sinT, bf16_t* __restrict__ Kb) {
  int s = blockIdx.x;
  int p = threadIdx.x;  // 0..255 = 4 kv heads x 64 pairs
  int kv = p >> 6, j = p & 63;
  float c = cosT[s * 64 + j], sn = sinT[s * 64 + j];
  const float* src = qkv + (size_t)s * 3072 + 2048 + kv * 128 + 2 * j;
  float x0 = src[0], x1 = src[1];
  bf16_t* dst = Kb + ((size_t)kv * S_LEN + s) * HD_ + 2 * j;
  dst[0] = (__bf16)(x0 * c - x1 * sn);
  dst[1] = (__bf16)(x0 * sn + x1 * c);
}

// ---------------------------------------------------------------- GEMM (m97 structure)
// A: MxK bf16 row-major.  B: NxK bf16 (i.e. W^T).  C: MxN fp32.
#define BM 128
#define BN 128
#define BK 64

__global__ __launch_bounds__(256) void gemm_bf16_kernel(const bf16_t* __restrict__ A,
    const bf16_t* __restrict__ B, float* __restrict__ C, int M, int N, int K) {
  __shared__ __attribute__((aligned(16))) bf16_t aL[BM * BK];
  __shared__ __attribute__((aligned(16))) bf16_t bL[BN * BK];
  const int tid = threadIdx.x;
  const int wave = tid >> 6, lane = tid & 63;
  const int wr = wave >> 1, wc = wave & 1;
  const int l15 = lane & 15, l4 = lane >> 4;
  const int bm = blockIdx.y * BM, bn = blockIdx.x * BN;

  f32x4 zero = {0.f, 0.f, 0.f, 0.f};
  f32x4 acc[4][4];
#pragma unroll
  for (int m = 0; m < 4; ++m)
#pragma unroll
    for (int n = 0; n < 4; ++n) acc[m][n] = zero;

  const bf16_t* aSrc[4];
  const bf16_t* bSrc[4];
  bf16_t* aDst[4];
  bf16_t* bDst[4];
#pragma unroll
  for (int i = 0; i < 4; ++i) {
    int ci = i * 256 + tid;
    int r = ci >> 3;
    int cl = (ci & 7) ^ (r & 7);
    aSrc[i] = A + (size_t)(bm + r) * K + cl * 8;
    bSrc[i] = B + (size_t)(bn + r) * K + cl * 8;
    aDst[i] = aL + (i * 256 + wave * 64) * 8;
    bDst[i] = bL + (i * 256 + wave * 64) * 8;
  }

  for (int kt = 0; kt < K; kt += BK) {
#pragma unroll
    for (int i = 0; i < 4; ++i) gload_lds16(aSrc[i] + kt, aDst[i]);
#pragma unroll
    for (int i = 0; i < 4; ++i) gload_lds16(bSrc[i] + kt, bDst[i]);
    __syncthreads();
#pragma unroll
    for (int t = 0; t < 2; ++t) {
      bf16x8 af[4], bfr[4];
#pragma unroll
      for (int f = 0; f < 4; ++f) {
        int Ra = wr * 64 + f * 16 + l15;
        int ca = (t * 4 + l4) ^ (Ra & 7);
        af[f] = *reinterpret_cast<const bf16x8*>(aL + Ra * 64 + ca * 8);
        int Rb = wc * 64 + f * 16 + l15;
        int cb = (t * 4 + l4) ^ (Rb & 7);
        bfr[f] = *reinterpret_cast<const bf16x8*>(bL + Rb * 64 + cb * 8);
      }
#pragma unroll
      for (int m = 0; m < 4; ++m)
#pragma unroll
        for (int n = 0; n < 4; ++n) acc[m][n] = MFMA16(af[m], bfr[n], acc[m][n]);
    }
    __syncthreads();
  }

#pragma unroll
  for (int m = 0; m < 4; ++m) {
    int row0 = bm + wr * 64 + m * 16 + l4 * 4;
#pragma unroll
    for (int n = 0; n < 4; ++n) {
      int col = bn + wc * 64 + n * 16 + l15;
#pragma unroll
      for (int r = 0; r < 4; ++r) C[(size_t)(row0 + r) * N + col] = acc[m][n][r];
    }
  }
}

// ---------------------------------------------------------------- differential flash attention
// Swapped-operand structure: S^T = mfma(K, Q) so q = lane (col), kv = regs.
// Qb: [H][S][HD].  Kb: [KV][S][HD].  VTb: [KV][HD][S].  All bf16.
// Grid: (16 pairs, 16 heads). Block: 4 waves x 16 q-rows; processes q-tile p then 31-p
// sequentially (33 KV-tile iterations each block -> perfect balance, 1 block/CU).
// K/V double-buffered in LDS with prefetch-before-compute.
#define P_PITCH 72  // bf16 elems per pS row (144 B) -> no XOR swizzle needed

__global__ __launch_bounds__(256) void diff_attn_kernel(const bf16_t* __restrict__ Qb,
    const bf16_t* __restrict__ Kb, const bf16_t* __restrict__ VTb,
    const float* __restrict__ lambda_param, bf16_t* __restrict__ attn) {
  const int h = blockIdx.y;
  const int kvh = h >> 2;  // REP = 4
  const int pr = blockIdx.x;  // pair index 0..15
  const int tid = threadIdx.x, wave = tid >> 6, lane = tid & 63;
  const int l15 = lane & 15, l4 = lane >> 4;

  __shared__ __attribute__((aligned(16))) bf16_t kB[2][64 * 128];  // [kv][hd], swizzled chunks
  __shared__ __attribute__((aligned(16))) bf16_t vB[2][64 * 128];  // [d][kv], swizzled chunks
  __shared__ __attribute__((aligned(16))) bf16_t pS[4][2][16 * P_PITCH];  // per-wave P^T: [q][kv]

  const bf16_t* kBase = Kb + (size_t)kvh * S_LEN * HD_;
  const bf16_t* vBase = VTb + (size_t)kvh * HD_ * S_LEN;
  // staging offsets (chunk ci = i*256 + tid; LDS dest linear, global src pre-swizzled)
  int kOff[4], vOff[4], dOff[4];
#pragma unroll
  for (int i = 0; i < 4; ++i) {
    int ci = i * 256 + tid;
    int kr = ci >> 4;
    kOff[i] = kr * HD_ + (((ci & 15) ^ (kr & 7)) * 8);
    int vr = ci >> 3;
    vOff[i] = vr * S_LEN + (((ci & 7) ^ (vr & 7)) * 8);
    dOff[i] = (i * 256 + wave * 64) * 8;
  }

  const float SC = 0.18033688f;  // (1/sqrt(64)) * log2(e); softmax runs in exp2 domain
  const float lam = 1.f / (1.f + __expf(-lambda_param[h]));
  const f32x4 zero = {0.f, 0.f, 0.f, 0.f};

  for (int ph = 0; ph < 2; ++ph) {
    const int jt = (ph == 0) ? pr : 31 - pr;  // q-tile index (64 rows)
    const int q0 = jt * 64;
    const int qg = q0 + wave * 16 + l15;  // this lane's q row (col of S^T)

    // Q fragments (B-operand: col=l15=q, k=hd). f=0,1 -> hd 0..63; f=2,3 -> hd 64..127
    const bf16_t* qp = Qb + ((size_t)h * S_LEN + qg) * HD_;
    bf16x8 qf[4];
#pragma unroll
    for (int f = 0; f < 4; ++f) qf[f] = *reinterpret_cast<const bf16x8*>(qp + f * 32 + l4 * 8);

    f32x4 o1[8], o2[8];
#pragma unroll
    for (int n = 0; n < 8; ++n) { o1[n] = zero; o2[n] = zero; }
    float m1 = -__builtin_inff(), m2 = -__builtin_inff(), l1 = 0.f, l2 = 0.f;

    // prologue: stage tile 0
#pragma unroll
    for (int i = 0; i < 4; ++i) gload_lds16(kBase + kOff[i], &kB[0][0] + dOff[i]);
#pragma unroll
    for (int i = 0; i < 4; ++i) gload_lds16(vBase + vOff[i], &vB[0][0] + dOff[i]);
    __syncthreads();

    for (int t = 0; t <= jt; ++t) {
      const int cur = t & 1;
      // prefetch next tile into the other buffer (overlaps with compute below)
      if (t < jt) {
        const size_t kv0n = (size_t)(t + 1) * 64;
#pragma unroll
        for (int i = 0; i < 4; ++i) gload_lds16(kBase + kv0n * HD_ + kOff[i], &kB[cur ^ 1][0] + dOff[i]);
#pragma unroll
        for (int i = 0; i < 4; ++i) gload_lds16(vBase + kv0n + vOff[i], &vB[cur ^ 1][0] + dOff[i]);
      }
      const bf16_t* kL = &kB[cur][0];
      const bf16_t* vL = &vB[cur][0];
      const int kv0 = t * 64;

      // S^T = K·Q^T : A=K rows(kv)=l15 per n-tile, B=Q cols(q)=l15.
      f32x4 s1[4], s2[4];
#pragma unroll
      for (int n = 0; n < 4; ++n) { s1[n] = zero; s2[n] = zero; }
#pragma unroll
      for (int tt = 0; tt < 2; ++tt) {
#pragma unroll
        for (int n = 0; n < 4; ++n) {
          const int Rk = n * 16 + l15;
          bf16x8 kf1 = *reinterpret_cast<const bf16x8*>(kL + Rk * 128 + (((tt * 4 + l4) ^ (Rk & 7)) * 8));
          s1[n] = MFMA16(kf1, qf[tt], s1[n]);
        }
      }
#pragma unroll
      for (int tt = 0; tt < 2; ++tt) {
#pragma unroll
        for (int n = 0; n < 4; ++n) {
          const int Rk = n * 16 + l15;
          bf16x8 kf2 = *reinterpret_cast<const bf16x8*>(kL + Rk * 128 + (((8 + tt * 4 + l4) ^ (Rk & 7)) * 8));
          s2[n] = MFMA16(kf2, qf[2 + tt], s2[n]);
        }
      }

      // mask + scale (exp2 domain). S^T: row (regs) = kv local = n*16 + l4*4 + r, col = q = qg.
      const bool diag = (t == jt);
#pragma unroll
      for (int n = 0; n < 4; ++n)
#pragma unroll
        for (int r = 0; r < 4; ++r) {
          float v1 = s1[n][r] * SC, v2 = s2[n][r] * SC;
          if (diag && (kv0 + n * 16 + l4 * 4 + r > qg)) { v1 = -1e30f; v2 = -1e30f; }
          s1[n][r] = v1; s2[n][r] = v2;
        }

      // ---- online softmax, half 1 (scalar m/l per lane; 2-stage cross-l4 reduce)
      float sc1, sc2;
      {
        float tmax = -3.4e38f;
#pragma unroll
        for (int n = 0; n < 4; ++n)
#pragma unroll
          for (int r = 0; r < 4; ++r) tmax = fmaxf(tmax, s1[n][r]);
        tmax = fmaxf(tmax, __shfl_xor(tmax, 16));
        tmax = fmaxf(tmax, __shfl_xor(tmax, 32));
        const float mn = fmaxf(m1, tmax);
        sc1 = __builtin_exp2f(m1 - mn);
        m1 = mn;
        float rs = 0.f;
#pragma unroll
        for (int n = 0; n < 4; ++n) {
          float e0 = __builtin_exp2f(s1[n][0] - mn);
          float e1 = __builtin_exp2f(s1[n][1] - mn);
          float e2 = __builtin_exp2f(s1[n][2] - mn);
          float e3 = __builtin_exp2f(s1[n][3] - mn);
          rs += (e0 + e1) + (e2 + e3);
          bf16x4 pk = {(__bf16)e0, (__bf16)e1, (__bf16)e2, (__bf16)e3};
          *reinterpret_cast<bf16x4*>(&pS[wave][0][l15 * P_PITCH + n * 16 + l4 * 4]) = pk;
        }
        rs += __shfl_xor(rs, 16);
        rs += __shfl_xor(rs, 32);
        l1 = l1 * sc1 + rs;
      }
      // ---- half 2
      {
        float tmax = -3.4e38f;
#pragma unroll
        for (int n = 0; n < 4; ++n)
#pragma unroll
          for (int r = 0; r < 4; ++r) tmax = fmaxf(tmax, s2[n][r]);
        tmax = fmaxf(tmax, __shfl_xor(tmax, 16));
        tmax = fmaxf(tmax, __shfl_xor(tmax, 32));
        const float mn = fmaxf(m2, tmax);
        sc2 = __builtin_exp2f(m2 - mn);
        m2 = mn;
        float rs = 0.f;
#pragma unroll
        for (int n = 0; n < 4; ++n) {
          float e0 = __builtin_exp2f(s2[n][0] - mn);
          float e1 = __builtin_exp2f(s2[n][1] - mn);
          float e2 = __builtin_exp2f(s2[n][2] - mn);
          float e3 = __builtin_exp2f(s2[n][3] - mn);
          rs += (e0 + e1) + (e2 + e3);
          bf16x4 pk = {(__bf16)e0, (__bf16)e1, (__bf16)e2, (__bf16)e3};
          *reinterpret_cast<bf16x4*>(&pS[wave][1][l15 * P_PITCH + n * 16 + l4 * 4]) = pk;
        }
        rs += __shfl_xor(rs, 16);
        rs += __shfl_xor(rs, 32);
        l2 = l2 * sc2 + rs;
      }
      // rescale O (uniform per lane)
#pragma unroll
      for (int n = 0; n < 8; ++n) { o1[n] *= sc1; o2[n] *= sc2; }

      // PV: O^T += V^T · P^T.  A = V^T (rows=d), B = P^T (cols=q, k=kv from pS).
#pragma unroll
      for (int kt = 0; kt < 2; ++kt) {
        bf16x8 pf1 = *reinterpret_cast<const bf16x8*>(&pS[wave][0][l15 * P_PITCH + kt * 32 + l4 * 8]);
        bf16x8 pf2 = *reinterpret_cast<const bf16x8*>(&pS[wave][1][l15 * P_PITCH + kt * 32 + l4 * 8]);
#pragma unroll
        for (int n = 0; n < 8; ++n) {
          const int Rv = n * 16 + l15;
          bf16x8 vf = *reinterpret_cast<const bf16x8*>(vL + Rv * 64 + (((kt * 4 + l4) ^ (Rv & 7)) * 8));
          o1[n] = MFMA16(vf, pf1, o1[n]);
          o2[n] = MFMA16(vf, pf2, o2[n]);
        }
      }
      __syncthreads();
    }

    // epilogue: O^T[d][q]: lane q=qg, d = n*16 + l4*4 + r
    const float i1 = 1.f / l1, i2 = lam / l2;
    bf16_t* orow = attn + (size_t)qg * D_MODEL + h * HD_;
#pragma unroll
    for (int n = 0; n < 8; ++n) {
      bf16x4 w = {(__bf16)((o1[n][0] * i1 - o2[n][0] * i2) * 0.5f),
                  (__bf16)((o1[n][1] * i1 - o2[n][1] * i2) * 0.5f),
                  (__bf16)((o1[n][2] * i1 - o2[n][2] * i2) * 0.5f),
                  (__bf16)((o1[n][3] * i1 - o2[n][3] * i2) * 0.5f)};
      *reinterpret_cast<bf16x4*>(orow + n * 16 + l4 * 4) = w;
    }
  }
}

// ---------------------------------------------------------------- launch
extern "C" void kernel_launch(void* const* d_in, const int* in_sizes, int n_in,
                              void* d_out, int out_size, void* d_ws, size_t ws_size,
                              hipStream_t stream) {
  const float* x    = (const float*)d_in[0];
  const float* fcos = (const float*)d_in[1];
  const float* fsin = (const float*)d_in[2];
  const float* Wq   = (const float*)d_in[3];
  const float* Wk   = (const float*)d_in[4];
  const float* Wv   = (const float*)d_in[5];
  const float* Wo   = (const float*)d_in[6];
  const float* lam  = (const float*)d_in[7];
  float* out = (float*)d_out;

  // workspace layout (52 MB total, phases overlap dead regions):
  //  [0,8)   xb  -> attnb      [8,20) WqkvT -> Qb/Kb/VT      [20,28) WoT      [28,52) QKV fp32
  char* w = (char*)d_ws;
  bf16_t* xb    = (bf16_t*)(w);
  bf16_t* attnb = (bf16_t*)(w);
  bf16_t* WqkvT = (bf16_t*)(w + (8ull << 20));
  bf16_t* Qb    = (bf16_t*)(w + (8ull << 20));
  bf16_t* Kb    = (bf16_t*)(w + (16ull << 20));
  bf16_t* VT    = (bf16_t*)(w + (18ull << 20));
  bf16_t* WoT   = (bf16_t*)(w + (20ull << 20));
  float*  QKV   = (float*) (w + (28ull << 20));

  dim3 tb(32, 32);
  cast_x_kernel<<<4096, 256, 0, stream>>>(x, xb, 1048576);
  transpose_cast_kernel<<<dim3(64, 64), tb, 0, stream>>>(Wq, WqkvT, 2048, 2048);
  transpose_cast_kernel<<<dim3(16, 64), tb, 0, stream>>>(Wk, WqkvT + 2048 * 2048, 512, 2048);
  transpose_cast_kernel<<<dim3(16, 64), tb, 0, stream>>>(Wv, WqkvT + 2560 * 2048, 512, 2048);
  transpose_cast_kernel<<<dim3(64, 64), tb, 0, stream>>>(Wo, WoT, 2048, 2048);

  gemm_bf16_kernel<<<dim3(24, 16), 256, 0, stream>>>(xb, WqkvT, QKV, 2048, 3072, 2048);

  rope_q_kernel<<<2048, 256, 0, stream>>>(QKV, fcos, fsin, Qb);
  rope_k_kernel<<<2048, 256, 0, stream>>>(QKV, fcos, fsin, Kb);
  transpose_cast_kernel<<<dim3(16, 64), tb, 0, stream>>>(QKV + 2560, VT, 3072, 2048);

  diff_attn_kernel<<<dim3(16, 16), 256, 0, stream>>>(Qb, Kb, VT, lam, attnb);

  gemm_bf16_kernel<<<dim3(16, 16), 256, 0, stream>>>(attnb, WoT, out, 2048, 2048, 2048);
}